// Round 3
// baseline (338.799 us; speedup 1.0000x reference)
//
#include <hip/hip_runtime.h>

#define T_MAX  50
#define D2_MAX 1923   // d2 = dx*dx + dy*dy, dx,dy in [-31,31] -> d2 in [0, 1922]

// ---------------------------------------------------------------------------
// Kernel 1: build M[t][d2] = prod_{s=1..t+1? no: s=1..t} (1 - exp(-d2/(2*beta_s)))
// for t = 1..T_MAX (stored at row t-1), d2 = 0..1922.
// 1923 threads, each owns one d2 value and walks the 50-step recurrence.
// ~96K entries total, a few microseconds.
// ---------------------------------------------------------------------------
__global__ __launch_bounds__(256) void gm_build_table(float* __restrict__ tab)
{
    const int v = blockIdx.x * 256 + threadIdx.x;
    if (v >= D2_MAX) return;
    const float d2 = (float)v;
    float m = 1.0f;
    #pragma unroll 1
    for (int s = 0; s < T_MAX; ++s) {
        const float beta = 1.0f + 0.1f * (float)s;          // beta_s, s = step-1
        const float sc   = (-0.5f * 1.44269504088896340736f) / beta;  // -log2e/(2*beta)
        const float g    = exp2f(d2 * sc);                  // exp(-d2/(2*beta))
        m = __builtin_fmaf(-g, m, m);                        // m *= (1 - g)
        tab[s * D2_MAX + v] = m;                             // row s = mask after t=s+1 steps
    }
}

// ---------------------------------------------------------------------------
// Kernel 2: one block per batch element. Stage the 7.7 KB row M[t_b-1][*] into
// LDS (coalesced), then per pixel: integer d2 -> LDS lookup -> multiply the
// 3 channels. No transcendentals in the hot path; pure streaming HBM.
// ---------------------------------------------------------------------------
__global__ __launch_bounds__(256) void gm_apply(
    const float* __restrict__ x0,
    const int*   __restrict__ t,
    const float* __restrict__ cx,
    const float* __restrict__ cy,
    const float* __restrict__ tab,
    float*       __restrict__ out)
{
    __shared__ float row[D2_MAX];

    const int b   = blockIdx.x;
    const int tid = threadIdx.x;

    const int tb  = t[b];                       // in [1, 50], block-uniform
    const int icx = __float2int_rn(cx[b]);      // cx/cy are exact integers
    const int icy = __float2int_rn(cy[b]);

    // Issue the x0 loads first so HBM latency hides under staging + barrier.
    const float4* __restrict__ x4 = (const float4*)(x0 + (size_t)b * 3072);
    float4 v0 = x4[tid];
    float4 v1 = x4[256 + tid];
    float4 v2 = x4[512 + tid];

    // Stage this batch's table row (1923 floats) into LDS, coalesced.
    const float* __restrict__ src = tab + (size_t)(tb - 1) * D2_MAX;
    #pragma unroll
    for (int i = tid; i < D2_MAX; i += 256) row[i] = src[i];
    __syncthreads();

    // Pixel p: col = p&31 (x), row = p>>5 (y); d2 is an integer in [0,1922].
    const int p0 = tid * 4;
    float m[4];
    #pragma unroll
    for (int k = 0; k < 4; ++k) {
        const int p  = p0 + k;
        const int dx = (p & 31) - icx;
        const int dy = (p >> 5) - icy;
        m[k] = row[dx * dx + dy * dy];
    }

    float4* __restrict__ o4 = (float4*)(out + (size_t)b * 3072);
    v0.x *= m[0]; v0.y *= m[1]; v0.z *= m[2]; v0.w *= m[3];
    v1.x *= m[0]; v1.y *= m[1]; v1.z *= m[2]; v1.w *= m[3];
    v2.x *= m[0]; v2.y *= m[1]; v2.z *= m[2]; v2.w *= m[3];
    o4[tid]       = v0;
    o4[256 + tid] = v1;
    o4[512 + tid] = v2;
}

extern "C" void kernel_launch(void* const* d_in, const int* in_sizes, int n_in,
                              void* d_out, int out_size, void* d_ws, size_t ws_size,
                              hipStream_t stream) {
    const float* x0 = (const float*)d_in[0];
    const int*   t  = (const int*)d_in[1];
    const float* cx = (const float*)d_in[2];
    const float* cy = (const float*)d_in[3];
    float* out = (float*)d_out;
    float* tab = (float*)d_ws;                  // 50*1923*4 B = 384,600 B scratch
    const int B = in_sizes[1];                  // 16384

    gm_build_table<<<(D2_MAX + 255) / 256, 256, 0, stream>>>(tab);
    gm_apply<<<B, 256, 0, stream>>>(x0, t, cx, cy, tab, out);
}